// Round 1
// baseline (666.217 us; speedup 1.0000x reference)
//
#include <hip/hip_runtime.h>
#include <math.h>

// ---------------------------------------------------------------------------
// TransformerBlock: B=2 S=2048 DIM=1024 H=16 hd=64 FFN=4096, fp32 in/out.
// Strategy: bf16 MFMA for all matmuls (threshold budgets bf16: 1.19e-1).
//   ln1 -> h1(bf16); weights cast+transposed to Bt[n][k] bf16;
//   QKV fused GEMM (N=3072); flash attention (S^T=K*Q^T orientation,
//   LDS round-trip for P layout transform, V pre-transposed dim-major);
//   WO GEMM + residual; ln2; W1 GEMM + exact GELU; W2 GEMM + residual.
// GEMM: m97 structure — 128x128 tile, BK=32, global_load_lds width 16,
//   4 waves each 64x64 (4x4 of 16x16x32 MFMA).
// ---------------------------------------------------------------------------

#define DIMSZ 1024
#define SEQ   2048
#define BATCH 2
#define NHEAD 16
#define HD    64
#define FFNSZ 4096
#define ROWS  (BATCH*SEQ)   // 4096

typedef __attribute__((ext_vector_type(8))) short bf8_t;   // 8 x bf16 (4 VGPR)
typedef __attribute__((ext_vector_type(4))) float f4_t;    // 4 x f32

// round-to-nearest-even float -> bf16 (bit pattern)
__device__ __forceinline__ unsigned short f2bf(float f) {
  union { float f; unsigned u; } c; c.f = f;
  unsigned u = c.u;
  return (unsigned short)((u + 0x7fffu + ((u >> 16) & 1u)) >> 16);
}

__device__ __forceinline__ void async16(const void* g, void* l) {
  __builtin_amdgcn_global_load_lds((const __attribute__((address_space(1))) void*)g,
                                   (__attribute__((address_space(3))) void*)l,
                                   16, 0, 0);
}

__device__ __forceinline__ f4_t mfma_bf16(bf8_t a, bf8_t b, f4_t c) {
  return __builtin_amdgcn_mfma_f32_16x16x32_bf16(a, b, c, 0, 0, 0);
}

// ---------------------------------------------------------------------------
// LayerNorm: one wave per row of 1024 fp32 -> bf16 out.
// grid = ROWS/4, block = 256 (4 waves)
// ---------------------------------------------------------------------------
__global__ __launch_bounds__(256) void ln_kernel(const float* __restrict__ x,
                                                 const float* __restrict__ w,
                                                 const float* __restrict__ b,
                                                 unsigned short* __restrict__ out) {
  int row  = blockIdx.x * 4 + (threadIdx.x >> 6);
  int lane = threadIdx.x & 63;
  const float4* xr = (const float4*)(x + (size_t)row * DIMSZ);
  float4 v[4];
  float s = 0.f, s2 = 0.f;
#pragma unroll
  for (int i = 0; i < 4; ++i) {
    v[i] = xr[lane + 64*i];
    s  += (v[i].x + v[i].y) + (v[i].z + v[i].w);
    s2 += (v[i].x*v[i].x + v[i].y*v[i].y) + (v[i].z*v[i].z + v[i].w*v[i].w);
  }
#pragma unroll
  for (int off = 32; off; off >>= 1) {
    s  += __shfl_xor(s,  off);
    s2 += __shfl_xor(s2, off);
  }
  float mean = s * (1.f/DIMSZ);
  float var  = s2 * (1.f/DIMSZ) - mean*mean;
  float rstd = rsqrtf(var + 1e-12f);
  const float4* wr = (const float4*)w;
  const float4* br = (const float4*)b;
#pragma unroll
  for (int i = 0; i < 4; ++i) {
    float4 wv = wr[lane + 64*i];
    float4 bv = br[lane + 64*i];
    ushort4 o;
    o.x = f2bf((v[i].x - mean) * rstd * wv.x + bv.x);
    o.y = f2bf((v[i].y - mean) * rstd * wv.y + bv.y);
    o.z = f2bf((v[i].z - mean) * rstd * wv.z + bv.z);
    o.w = f2bf((v[i].w - mean) * rstd * wv.w + bv.w);
    *(ushort4*)(out + (size_t)row * DIMSZ + (size_t)(lane + 64*i) * 4) = o;
  }
}

// ---------------------------------------------------------------------------
// Weight cast+transpose: w[K][N] fp32 -> wT[N][K] bf16. 32x32 tiles.
// grid = (N/32, K/32), block = 256
// ---------------------------------------------------------------------------
__global__ __launch_bounds__(256) void wtrans_kernel(const float* __restrict__ w,
                                                     unsigned short* __restrict__ wT,
                                                     int K, int N) {
  __shared__ float t[32][33];
  int tx = threadIdx.x & 31, ty = threadIdx.x >> 5;
  int n0 = blockIdx.x * 32, k0 = blockIdx.y * 32;
#pragma unroll
  for (int i = 0; i < 4; ++i)
    t[ty + 8*i][tx] = w[(size_t)(k0 + ty + 8*i) * N + n0 + tx];
  __syncthreads();
#pragma unroll
  for (int i = 0; i < 4; ++i)
    wT[(size_t)(n0 + ty + 8*i) * K + k0 + tx] = f2bf(t[tx][ty + 8*i]);
}

// ---------------------------------------------------------------------------
// V transpose: qkv[(b*S+s)*3072 + 2048 + h*64 + d] -> vt[(bh*64+d)*S + s]
// grid = (S/64, B*H), block = 256
// ---------------------------------------------------------------------------
__global__ __launch_bounds__(256) void vt_kernel(const unsigned short* __restrict__ qkv,
                                                 unsigned short* __restrict__ vt) {
  __shared__ unsigned short tile[64][65];
  int bh = blockIdx.y, b = bh >> 4, h = bh & 15;
  int s0 = blockIdx.x * 64;
  int tx = threadIdx.x & 63, ty = threadIdx.x >> 6;
#pragma unroll
  for (int i = 0; i < 16; ++i) {
    int s = ty + i*4;
    tile[s][tx] = qkv[((size_t)(b*SEQ) + s0 + s) * 3072 + 2048 + h*HD + tx];
  }
  __syncthreads();
#pragma unroll
  for (int i = 0; i < 16; ++i) {
    int d = ty + i*4;
    vt[((size_t)bh * HD + d) * SEQ + s0 + tx] = tile[tx][d];
  }
}

// ---------------------------------------------------------------------------
// GEMM: C[M,N] = epi( A[M,K] @ Bt[N,K]^T )   (A, Bt bf16 row-major)
// EPI: 0 = bf16 out; 1 = bf16 gelu(exact) out; 2 = f32 out, += res
// block 256 (4 waves, 2x2 of 64x64), tile 128x128, BK=32.
// grid = (N/128, M/128). M,N,K all multiples of tile — no bounds checks.
// ---------------------------------------------------------------------------
template<int EPI>
__global__ __launch_bounds__(256) void gemm_bt(const unsigned short* __restrict__ A,
                                               const unsigned short* __restrict__ Bt,
                                               void* __restrict__ Cv,
                                               const float* __restrict__ res,
                                               int M, int N, int K) {
  __shared__ unsigned short As[128*32];
  __shared__ unsigned short Bs[128*32];
  int tid  = threadIdx.x;
  int wv   = tid >> 6, lane = tid & 63, quad = lane >> 4, ml = lane & 15;
  int wrow = (wv >> 1) * 64, wcol = (wv & 1) * 64;
  const unsigned short* Ab = A  + (size_t)blockIdx.y * 128 * K;
  const unsigned short* Bb = Bt + (size_t)blockIdx.x * 128 * K;

  f4_t acc[4][4];
#pragma unroll
  for (int i = 0; i < 4; ++i)
#pragma unroll
    for (int j = 0; j < 4; ++j) acc[i][j] = (f4_t){0.f, 0.f, 0.f, 0.f};

  int r0 = tid >> 2, c0 = (tid & 3) * 8;   // 8 bf16 = 16B per lane

  for (int k0 = 0; k0 < K; k0 += 32) {
    // stage 128x32 A and Bt tiles: 512 x 16B each, 2 iters of 256 lanes
    async16(Ab + (size_t)r0 * K + k0 + c0,        &As[(size_t)tid * 8]);
    async16(Ab + (size_t)(r0+64) * K + k0 + c0,   &As[((size_t)tid + 256) * 8]);
    async16(Bb + (size_t)r0 * K + k0 + c0,        &Bs[(size_t)tid * 8]);
    async16(Bb + (size_t)(r0+64) * K + k0 + c0,   &Bs[((size_t)tid + 256) * 8]);
    __syncthreads();   // drains vmcnt (global_load_lds) per m97 structure

    bf8_t af[4], bfr[4];
#pragma unroll
    for (int i = 0; i < 4; ++i)
      af[i] = *(const bf8_t*)(&As[(wrow + i*16 + ml) * 32 + quad * 8]);
#pragma unroll
    for (int j = 0; j < 4; ++j)
      bfr[j] = *(const bf8_t*)(&Bs[(wcol + j*16 + ml) * 32 + quad * 8]);
#pragma unroll
    for (int i = 0; i < 4; ++i)
#pragma unroll
      for (int j = 0; j < 4; ++j)
        acc[i][j] = mfma_bf16(af[i], bfr[j], acc[i][j]);
    __syncthreads();
  }

  // epilogue: C/D layout col=lane&15, row=quad*4+reg  [verified m89/m91]
#pragma unroll
  for (int i = 0; i < 4; ++i) {
    int grow = blockIdx.y * 128 + wrow + i*16 + quad*4;
#pragma unroll
    for (int j = 0; j < 4; ++j) {
      int gcol = blockIdx.x * 128 + wcol + j*16 + ml;
#pragma unroll
      for (int r = 0; r < 4; ++r) {
        size_t off = (size_t)(grow + r) * N + gcol;
        float v = acc[i][j][r];
        if constexpr (EPI == 2) {
          ((float*)Cv)[off] = res[off] + v;
        } else {
          if constexpr (EPI == 1)
            v = 0.5f * v * (1.f + erff(v * 0.70710678118654752f));
          ((unsigned short*)Cv)[off] = f2bf(v);
        }
      }
    }
  }
}

// ---------------------------------------------------------------------------
// Flash attention. grid = (S/64, B*H), block 256 (4 waves x 16 q-rows).
// Computes S^T = K·Q^T (MFMA A=K, B=Q), so per-lane q = lane&15 (one alpha
// per lane), keys live in regs (quad*4+r). P^T -> B-operand layout via LDS.
// O^T = V^T·P^T with vt dim-major so all frag loads are contiguous 16B.
// ---------------------------------------------------------------------------
__global__ __launch_bounds__(256) void attn_kernel(const unsigned short* __restrict__ qkv,
                                                   const unsigned short* __restrict__ vt,
                                                   const float* __restrict__ mask,
                                                   unsigned short* __restrict__ attnout) {
  __shared__ unsigned short Pb[4][16][32];   // per-wave P^T buffer [q][key]
  int bh = blockIdx.y, b = bh >> 4, h = bh & 15;
  int wv = threadIdx.x >> 6, lane = threadIdx.x & 63;
  int quad = lane >> 4, ml = lane & 15;
  int q = blockIdx.x * 64 + wv * 16 + ml;    // this lane's q row (in seq)

  // Q fragment, B-operand layout: n=q (lane&15), k=d (quad*8+j)
  const unsigned short* qrow = qkv + ((size_t)(b*SEQ) + q) * 3072 + h*HD;
  bf8_t qf0 = *(const bf8_t*)(qrow + quad*8);
  bf8_t qf1 = *(const bf8_t*)(qrow + 32 + quad*8);
  const unsigned short* kbase = qkv + (size_t)(b*SEQ) * 3072 + DIMSZ + h*HD;
  const unsigned short* vbase = vt + (size_t)bh * HD * SEQ;
  const float* mrow = mask + (size_t)q * SEQ;

  f4_t O[4];
#pragma unroll
  for (int dt = 0; dt < 4; ++dt) O[dt] = (f4_t){0.f, 0.f, 0.f, 0.f};
  float mR = -__builtin_inff(), lR = 0.f;

  for (int t0 = 0; t0 < SEQ; t0 += 32) {
    float sfa[2][4];
    float cmax = -__builtin_inff();
#pragma unroll
    for (int tt = 0; tt < 2; ++tt) {
      const unsigned short* krow = kbase + (size_t)(t0 + tt*16 + ml) * 3072;
      bf8_t kf0 = *(const bf8_t*)(krow + quad*8);
      bf8_t kf1 = *(const bf8_t*)(krow + 32 + quad*8);
      f4_t s = (f4_t){0.f, 0.f, 0.f, 0.f};
      s = mfma_bf16(kf0, qf0, s);       // d 0..31
      s = mfma_bf16(kf1, qf1, s);       // d 32..63
      // S^T tile: lane holds keys t0+tt*16+quad*4+r for its q
      float4 mv = *(const float4*)(mrow + t0 + tt*16 + quad*4);
      float mvals[4] = {mv.x, mv.y, mv.z, mv.w};
#pragma unroll
      for (int r = 0; r < 4; ++r) {
        float val = s[r] * 0.125f + mvals[r];
        sfa[tt][r] = val;
        cmax = fmaxf(cmax, val);
      }
    }
    // reduce over the 4 lanes sharing this q (quads)
    cmax = fmaxf(cmax, __shfl_xor(cmax, 16));
    cmax = fmaxf(cmax, __shfl_xor(cmax, 32));
    float mnew  = fmaxf(mR, cmax);
    float alpha = __expf(mR - mnew);   // -inf first iter -> 0
    float psum = 0.f;
#pragma unroll
    for (int tt = 0; tt < 2; ++tt) {
      float p0 = __expf(sfa[tt][0] - mnew);
      float p1 = __expf(sfa[tt][1] - mnew);
      float p2 = __expf(sfa[tt][2] - mnew);
      float p3 = __expf(sfa[tt][3] - mnew);
      psum += (p0 + p1) + (p2 + p3);
      ushort4 pw;
      pw.x = f2bf(p0); pw.y = f2bf(p1); pw.z = f2bf(p2); pw.w = f2bf(p3);
      *(ushort4*)(&Pb[wv][ml][tt*16 + quad*4]) = pw;   // P^T[q][key], 4 keys
    }
    psum += __shfl_xor(psum, 16);
    psum += __shfl_xor(psum, 32);
    lR = lR * alpha + psum;
    mR = mnew;
#pragma unroll
    for (int dt = 0; dt < 4; ++dt)
#pragma unroll
      for (int r = 0; r < 4; ++r) O[dt][r] *= alpha;
    __syncthreads();   // P writes -> P reads (uniform trip count)
    // P^T B-operand frag: n=q (lane&15), k=key (quad*8+j)
    bf8_t pf = *(const bf8_t*)(&Pb[wv][ml][quad*8]);
#pragma unroll
    for (int dt = 0; dt < 4; ++dt) {
      // V^T A-operand frag: m=d (lane&15), k=key (quad*8+j), contiguous in vt
      bf8_t vf = *(const bf8_t*)(vbase + (size_t)(dt*16 + ml) * SEQ + t0 + quad*8);
      O[dt] = mfma_bf16(vf, pf, O[dt]);
    }
    __syncthreads();
  }

  float linv = 1.f / lR;
#pragma unroll
  for (int dt = 0; dt < 4; ++dt) {
    ushort4 o;
    o.x = f2bf(O[dt][0] * linv);
    o.y = f2bf(O[dt][1] * linv);
    o.z = f2bf(O[dt][2] * linv);
    o.w = f2bf(O[dt][3] * linv);
    // O^T[d][q]: row s=q, col h*64 + dt*16 + quad*4 + r
    *(ushort4*)(attnout + ((size_t)(b*SEQ) + q) * DIMSZ + h*HD + dt*16 + quad*4) = o;
  }
}

// ---------------------------------------------------------------------------
extern "C" void kernel_launch(void* const* d_in, const int* in_sizes, int n_in,
                              void* d_out, int out_size, void* d_ws, size_t ws_size,
                              hipStream_t stream) {
  const float* x    = (const float*)d_in[0];
  const float* mask = (const float*)d_in[1];
  const float* wq   = (const float*)d_in[2];
  const float* wk   = (const float*)d_in[3];
  const float* wvp  = (const float*)d_in[4];
  const float* wo   = (const float*)d_in[5];
  const float* w1   = (const float*)d_in[6];
  const float* w2   = (const float*)d_in[7];
  const float* ln1w = (const float*)d_in[8];
  const float* ln1b = (const float*)d_in[9];
  const float* ln2w = (const float*)d_in[10];
  const float* ln2b = (const float*)d_in[11];
  float* out = (float*)d_out;

  // workspace layout (bytes), total 92,274,688 (~88 MiB)
  char* ws = (char*)d_ws;
  unsigned short* wqkvT  = (unsigned short*)(ws + 0);           //  6 MiB [3072][1024]
  unsigned short* woT    = (unsigned short*)(ws + 6291456);     //  2 MiB [1024][1024]
  unsigned short* w1T    = (unsigned short*)(ws + 8388608);     //  8 MiB [4096][1024]
  unsigned short* w2T    = (unsigned short*)(ws + 16777216);    //  8 MiB [1024][4096]
  unsigned short* attno  = (unsigned short*)(ws + 25165824);    //  8 MiB [4096][1024]
  float*          x2     = (float*)         (ws + 33554432);    // 16 MiB [4096][1024]
  unsigned short* hbuf   = (unsigned short*)(ws + 50331648);    //  8 MiB h1 then h2
  unsigned short* qkvb   = (unsigned short*)(ws + 58720256);    // 24 MiB [4096][3072]
  unsigned short* vtb    = (unsigned short*)(ws + 83886080);    //  8 MiB [32][64][2048]
  unsigned short* gbuf   = (unsigned short*)(ws + 58720256);    // 32 MiB, reuses qkv+vt

  // 1. LN1: x -> h1 (bf16)
  ln_kernel<<<ROWS/4, 256, 0, stream>>>(x, ln1w, ln1b, hbuf);
  // 2. weight cast+transpose
  wtrans_kernel<<<dim3(32, 32),  256, 0, stream>>>(wq,  wqkvT,                 1024, 1024);
  wtrans_kernel<<<dim3(32, 32),  256, 0, stream>>>(wk,  wqkvT + 1024*1024,     1024, 1024);
  wtrans_kernel<<<dim3(32, 32),  256, 0, stream>>>(wvp, wqkvT + 2*1024*1024,   1024, 1024);
  wtrans_kernel<<<dim3(32, 32),  256, 0, stream>>>(wo,  woT,                   1024, 1024);
  wtrans_kernel<<<dim3(128, 32), 256, 0, stream>>>(w1,  w1T,                   1024, 4096);
  wtrans_kernel<<<dim3(32, 128), 256, 0, stream>>>(w2,  w2T,                   4096, 1024);
  // 3. fused QKV projection: [4096,1024] @ [1024,3072] -> bf16
  gemm_bt<0><<<dim3(3072/128, 4096/128), 256, 0, stream>>>(hbuf, wqkvT, qkvb, nullptr, ROWS, 3072, 1024);
  // 4. V -> dim-major
  vt_kernel<<<dim3(SEQ/64, BATCH*NHEAD), 256, 0, stream>>>(qkvb, vtb);
  // 5. flash attention -> attno (bf16)
  attn_kernel<<<dim3(SEQ/64, BATCH*NHEAD), 256, 0, stream>>>(qkvb, vtb, mask, attno);
  // 6. x2 = x + attn @ wo  (fp32)
  gemm_bt<2><<<dim3(1024/128, 4096/128), 256, 0, stream>>>(attno, woT, x2, x, ROWS, 1024, 1024);
  // 7. LN2: x2 -> h2 (bf16)
  ln_kernel<<<ROWS/4, 256, 0, stream>>>(x2, ln2w, ln2b, hbuf);
  // 8. g = gelu(h2 @ w1)  (bf16)
  gemm_bt<1><<<dim3(4096/128, 4096/128), 256, 0, stream>>>(hbuf, w1T, gbuf, nullptr, ROWS, FFNSZ, 1024);
  // 9. out = x2 + g @ w2  (fp32)
  gemm_bt<2><<<dim3(1024/128, 4096/128), 256, 0, stream>>>(gbuf, w2T, out, x2, ROWS, 1024, 4096);

  (void)in_sizes; (void)n_in; (void)out_size; (void)ws_size;
}

// Round 2
// 491.442 us; speedup vs baseline: 1.3556x; 1.3556x over previous
//
#include <hip/hip_runtime.h>
#include <math.h>

// ---------------------------------------------------------------------------
// TransformerBlock: B=2 S=2048 DIM=1024 H=16 hd=64 FFN=4096, fp32 in/out.
// bf16 MFMA everywhere. R1: attention restructured — 64-key chunks, K/V/mask
// staged in LDS (global_load_lds for K/V, reg->padded-LDS for mask), P
// wave-private (no barriers), 2 barriers/chunk instead of 4 per 32 keys.
// ---------------------------------------------------------------------------

#define DIMSZ 1024
#define SEQ   2048
#define BATCH 2
#define NHEAD 16
#define HD    64
#define FFNSZ 4096
#define ROWS  (BATCH*SEQ)   // 4096

typedef __attribute__((ext_vector_type(8))) short bf8_t;   // 8 x bf16 (4 VGPR)
typedef __attribute__((ext_vector_type(4))) float f4_t;    // 4 x f32

// round-to-nearest-even float -> bf16 (bit pattern)
__device__ __forceinline__ unsigned short f2bf(float f) {
  union { float f; unsigned u; } c; c.f = f;
  unsigned u = c.u;
  return (unsigned short)((u + 0x7fffu + ((u >> 16) & 1u)) >> 16);
}

__device__ __forceinline__ void async16(const void* g, void* l) {
  __builtin_amdgcn_global_load_lds((const __attribute__((address_space(1))) void*)g,
                                   (__attribute__((address_space(3))) void*)l,
                                   16, 0, 0);
}

__device__ __forceinline__ f4_t mfma_bf16(bf8_t a, bf8_t b, f4_t c) {
  return __builtin_amdgcn_mfma_f32_16x16x32_bf16(a, b, c, 0, 0, 0);
}

// ---------------------------------------------------------------------------
// LayerNorm: one wave per row of 1024 fp32 -> bf16 out.
// ---------------------------------------------------------------------------
__global__ __launch_bounds__(256) void ln_kernel(const float* __restrict__ x,
                                                 const float* __restrict__ w,
                                                 const float* __restrict__ b,
                                                 unsigned short* __restrict__ out) {
  int row  = blockIdx.x * 4 + (threadIdx.x >> 6);
  int lane = threadIdx.x & 63;
  const float4* xr = (const float4*)(x + (size_t)row * DIMSZ);
  float4 v[4];
  float s = 0.f, s2 = 0.f;
#pragma unroll
  for (int i = 0; i < 4; ++i) {
    v[i] = xr[lane + 64*i];
    s  += (v[i].x + v[i].y) + (v[i].z + v[i].w);
    s2 += (v[i].x*v[i].x + v[i].y*v[i].y) + (v[i].z*v[i].z + v[i].w*v[i].w);
  }
#pragma unroll
  for (int off = 32; off; off >>= 1) {
    s  += __shfl_xor(s,  off);
    s2 += __shfl_xor(s2, off);
  }
  float mean = s * (1.f/DIMSZ);
  float var  = s2 * (1.f/DIMSZ) - mean*mean;
  float rstd = rsqrtf(var + 1e-12f);
  const float4* wr = (const float4*)w;
  const float4* br = (const float4*)b;
#pragma unroll
  for (int i = 0; i < 4; ++i) {
    float4 wv = wr[lane + 64*i];
    float4 bv = br[lane + 64*i];
    ushort4 o;
    o.x = f2bf((v[i].x - mean) * rstd * wv.x + bv.x);
    o.y = f2bf((v[i].y - mean) * rstd * wv.y + bv.y);
    o.z = f2bf((v[i].z - mean) * rstd * wv.z + bv.z);
    o.w = f2bf((v[i].w - mean) * rstd * wv.w + bv.w);
    *(ushort4*)(out + (size_t)row * DIMSZ + (size_t)(lane + 64*i) * 4) = o;
  }
}

// ---------------------------------------------------------------------------
// Weight cast+transpose: w[K][N] fp32 -> wT[N][K] bf16. 32x32 tiles.
// ---------------------------------------------------------------------------
__global__ __launch_bounds__(256) void wtrans_kernel(const float* __restrict__ w,
                                                     unsigned short* __restrict__ wT,
                                                     int K, int N) {
  __shared__ float t[32][33];
  int tx = threadIdx.x & 31, ty = threadIdx.x >> 5;
  int n0 = blockIdx.x * 32, k0 = blockIdx.y * 32;
#pragma unroll
  for (int i = 0; i < 4; ++i)
    t[ty + 8*i][tx] = w[(size_t)(k0 + ty + 8*i) * N + n0 + tx];
  __syncthreads();
#pragma unroll
  for (int i = 0; i < 4; ++i)
    wT[(size_t)(n0 + ty + 8*i) * K + k0 + tx] = f2bf(t[tx][ty + 8*i]);
}

// ---------------------------------------------------------------------------
// V transpose: qkv[(b*S+s)*3072 + 2048 + h*64 + d] -> vt[(bh*64+d)*S + s]
// ---------------------------------------------------------------------------
__global__ __launch_bounds__(256) void vt_kernel(const unsigned short* __restrict__ qkv,
                                                 unsigned short* __restrict__ vt) {
  __shared__ unsigned short tile[64][65];
  int bh = blockIdx.y, b = bh >> 4, h = bh & 15;
  int s0 = blockIdx.x * 64;
  int tx = threadIdx.x & 63, ty = threadIdx.x >> 6;
#pragma unroll
  for (int i = 0; i < 16; ++i) {
    int s = ty + i*4;
    tile[s][tx] = qkv[((size_t)(b*SEQ) + s0 + s) * 3072 + 2048 + h*HD + tx];
  }
  __syncthreads();
#pragma unroll
  for (int i = 0; i < 16; ++i) {
    int d = ty + i*4;
    vt[((size_t)bh * HD + d) * SEQ + s0 + tx] = tile[tx][d];
  }
}

// ---------------------------------------------------------------------------
// GEMM: C[M,N] = epi( A[M,K] @ Bt[N,K]^T )   (m97 structure, unchanged)
// ---------------------------------------------------------------------------
template<int EPI>
__global__ __launch_bounds__(256) void gemm_bt(const unsigned short* __restrict__ A,
                                               const unsigned short* __restrict__ Bt,
                                               void* __restrict__ Cv,
                                               const float* __restrict__ res,
                                               int M, int N, int K) {
  __shared__ unsigned short As[128*32];
  __shared__ unsigned short Bs[128*32];
  int tid  = threadIdx.x;
  int wv   = tid >> 6, lane = tid & 63, quad = lane >> 4, ml = lane & 15;
  int wrow = (wv >> 1) * 64, wcol = (wv & 1) * 64;
  const unsigned short* Ab = A  + (size_t)blockIdx.y * 128 * K;
  const unsigned short* Bb = Bt + (size_t)blockIdx.x * 128 * K;

  f4_t acc[4][4];
#pragma unroll
  for (int i = 0; i < 4; ++i)
#pragma unroll
    for (int j = 0; j < 4; ++j) acc[i][j] = (f4_t){0.f, 0.f, 0.f, 0.f};

  int r0 = tid >> 2, c0 = (tid & 3) * 8;

  for (int k0 = 0; k0 < K; k0 += 32) {
    async16(Ab + (size_t)r0 * K + k0 + c0,        &As[(size_t)tid * 8]);
    async16(Ab + (size_t)(r0+64) * K + k0 + c0,   &As[((size_t)tid + 256) * 8]);
    async16(Bb + (size_t)r0 * K + k0 + c0,        &Bs[(size_t)tid * 8]);
    async16(Bb + (size_t)(r0+64) * K + k0 + c0,   &Bs[((size_t)tid + 256) * 8]);
    __syncthreads();

    bf8_t af[4], bfr[4];
#pragma unroll
    for (int i = 0; i < 4; ++i)
      af[i] = *(const bf8_t*)(&As[(wrow + i*16 + ml) * 32 + quad * 8]);
#pragma unroll
    for (int j = 0; j < 4; ++j)
      bfr[j] = *(const bf8_t*)(&Bs[(wcol + j*16 + ml) * 32 + quad * 8]);
#pragma unroll
    for (int i = 0; i < 4; ++i)
#pragma unroll
      for (int j = 0; j < 4; ++j)
        acc[i][j] = mfma_bf16(af[i], bfr[j], acc[i][j]);
    __syncthreads();
  }

#pragma unroll
  for (int i = 0; i < 4; ++i) {
    int grow = blockIdx.y * 128 + wrow + i*16 + quad*4;
#pragma unroll
    for (int j = 0; j < 4; ++j) {
      int gcol = blockIdx.x * 128 + wcol + j*16 + ml;
#pragma unroll
      for (int r = 0; r < 4; ++r) {
        size_t off = (size_t)(grow + r) * N + gcol;
        float v = acc[i][j][r];
        if constexpr (EPI == 2) {
          ((float*)Cv)[off] = res[off] + v;
        } else {
          if constexpr (EPI == 1)
            v = 0.5f * v * (1.f + erff(v * 0.70710678118654752f));
          ((unsigned short*)Cv)[off] = f2bf(v);
        }
      }
    }
  }
}

// ---------------------------------------------------------------------------
// Flash attention, R1. grid = (S/64, B*H), block 256 (4 waves x 16 q-rows).
// 64-key chunks. K/V staged via global_load_lds into split-32 LDS tiles
// (m97 bank pattern); mask staged reg->padded LDS (coalesced global reads);
// P wave-private padded LDS (no barriers). 2 barriers per chunk.
// S^T = K·Q^T (A=K m=key, B=Q n=q); O^T = V^T·P^T.
// ---------------------------------------------------------------------------
__global__ __launch_bounds__(256) void attn_kernel(const unsigned short* __restrict__ qkv,
                                                   const unsigned short* __restrict__ vt,
                                                   const float* __restrict__ mask,
                                                   unsigned short* __restrict__ attnout) {
  __shared__ unsigned short Ks[2][64][32];   // [d-half][key][d32]   8 KB
  __shared__ unsigned short Vs[2][64][32];   // [key-half][d][k32]   8 KB
  __shared__ float          Ms[64][68];      // mask tile, padded    17 KB
  __shared__ unsigned short Ps[4][16][72];   // per-wave P^T, padded 9 KB

  int bh = blockIdx.y, b = bh >> 4, h = bh & 15;
  int tid = threadIdx.x;
  int wv = tid >> 6, lane = tid & 63;
  int quad = lane >> 4, ml = lane & 15;
  int q0 = blockIdx.x * 64;
  int q  = q0 + wv * 16 + ml;               // this lane's q row

  // Q fragment, B-operand layout: n=q (lane&15), k=d (quad*8+j)
  const unsigned short* qrow = qkv + ((size_t)(b*SEQ) + q) * 3072 + h*HD;
  bf8_t qf0 = *(const bf8_t*)(qrow + quad*8);
  bf8_t qf1 = *(const bf8_t*)(qrow + 32 + quad*8);

  const unsigned short* kbase = qkv + (size_t)(b*SEQ) * 3072 + DIMSZ + h*HD;
  const unsigned short* vbase = vt + (size_t)bh * HD * SEQ;

  // staging coords
  int srow = tid >> 2;            // 0..63
  int scol = (tid & 3) * 8;       // 0,8,16,24 (ushorts)
  int mrow = tid >> 4;            // 0..15
  int mcol = (tid & 15) * 4;      // 0..60 (floats)

  f4_t O[4];
#pragma unroll
  for (int dt = 0; dt < 4; ++dt) O[dt] = (f4_t){0.f, 0.f, 0.f, 0.f};
  float mR = -__builtin_inff(), lR = 0.f;

  for (int t0 = 0; t0 < SEQ; t0 += 64) {
    __syncthreads();   // previous chunk's reads done before overwrite
    // --- stage K (two d-halves) and V^T (two key-halves) ---
#pragma unroll
    for (int dh = 0; dh < 2; ++dh)
      async16(kbase + ((size_t)(t0 + srow)) * 3072 + dh*32 + scol,
              &Ks[dh][0][0] + (size_t)tid * 8);
#pragma unroll
    for (int kc = 0; kc < 2; ++kc)
      async16(vbase + (size_t)srow * SEQ + t0 + kc*32 + scol,
              &Vs[kc][0][0] + (size_t)tid * 8);
    // --- stage mask tile (coalesced 256B rows -> padded LDS) ---
#pragma unroll
    for (int it = 0; it < 4; ++it) {
      float4 mv = *(const float4*)(mask + (size_t)(q0 + mrow + it*16) * SEQ + t0 + mcol);
      *(float4*)(&Ms[mrow + it*16][mcol]) = mv;
    }
    __syncthreads();   // staging visible (drains vmcnt + lgkmcnt)

    // --- S^T = K·Q^T over 64 keys ---
    float sfa[4][4];
    float cmax = -__builtin_inff();
#pragma unroll
    for (int mt = 0; mt < 4; ++mt) {
      bf8_t kf0 = *(const bf8_t*)(&Ks[0][mt*16 + ml][quad*8]);
      bf8_t kf1 = *(const bf8_t*)(&Ks[1][mt*16 + ml][quad*8]);
      f4_t s = (f4_t){0.f, 0.f, 0.f, 0.f};
      s = mfma_bf16(kf0, qf0, s);
      s = mfma_bf16(kf1, qf1, s);
      float4 mv = *(const float4*)(&Ms[wv*16 + ml][mt*16 + quad*4]);
      float mvals[4] = {mv.x, mv.y, mv.z, mv.w};
#pragma unroll
      for (int r = 0; r < 4; ++r) {
        float val = s[r] * 0.125f + mvals[r];
        sfa[mt][r] = val;
        cmax = fmaxf(cmax, val);
      }
    }
    cmax = fmaxf(cmax, __shfl_xor(cmax, 16));
    cmax = fmaxf(cmax, __shfl_xor(cmax, 32));
    float mnew  = fmaxf(mR, cmax);
    float alpha = __expf(mR - mnew);
    float psum = 0.f;
#pragma unroll
    for (int mt = 0; mt < 4; ++mt) {
      float p0 = __expf(sfa[mt][0] - mnew);
      float p1 = __expf(sfa[mt][1] - mnew);
      float p2 = __expf(sfa[mt][2] - mnew);
      float p3 = __expf(sfa[mt][3] - mnew);
      psum += (p0 + p1) + (p2 + p3);
      ushort4 pw;
      pw.x = f2bf(p0); pw.y = f2bf(p1); pw.z = f2bf(p2); pw.w = f2bf(p3);
      *(ushort4*)(&Ps[wv][ml][mt*16 + quad*4]) = pw;
    }
    psum += __shfl_xor(psum, 16);
    psum += __shfl_xor(psum, 32);
    lR = lR * alpha + psum;
    mR = mnew;
#pragma unroll
    for (int dt = 0; dt < 4; ++dt)
#pragma unroll
      for (int r = 0; r < 4; ++r) O[dt][r] *= alpha;

    // --- O^T += V^T·P^T (P wave-private: no barrier, lgkmcnt orders it) ---
#pragma unroll
    for (int kc = 0; kc < 2; ++kc) {
      bf8_t pf = *(const bf8_t*)(&Ps[wv][ml][kc*32 + quad*8]);
#pragma unroll
      for (int dt = 0; dt < 4; ++dt) {
        bf8_t vf = *(const bf8_t*)(&Vs[kc][dt*16 + ml][quad*8]);
        O[dt] = mfma_bf16(vf, pf, O[dt]);
      }
    }
  }

  float linv = 1.f / lR;
#pragma unroll
  for (int dt = 0; dt < 4; ++dt) {
    ushort4 o;
    o.x = f2bf(O[dt][0] * linv);
    o.y = f2bf(O[dt][1] * linv);
    o.z = f2bf(O[dt][2] * linv);
    o.w = f2bf(O[dt][3] * linv);
    *(ushort4*)(attnout + ((size_t)(b*SEQ) + q) * DIMSZ + h*HD + dt*16 + quad*4) = o;
  }
}

// ---------------------------------------------------------------------------
extern "C" void kernel_launch(void* const* d_in, const int* in_sizes, int n_in,
                              void* d_out, int out_size, void* d_ws, size_t ws_size,
                              hipStream_t stream) {
  const float* x    = (const float*)d_in[0];
  const float* mask = (const float*)d_in[1];
  const float* wq   = (const float*)d_in[2];
  const float* wk   = (const float*)d_in[3];
  const float* wvp  = (const float*)d_in[4];
  const float* wo   = (const float*)d_in[5];
  const float* w1   = (const float*)d_in[6];
  const float* w2   = (const float*)d_in[7];
  const float* ln1w = (const float*)d_in[8];
  const float* ln1b = (const float*)d_in[9];
  const float* ln2w = (const float*)d_in[10];
  const float* ln2b = (const float*)d_in[11];
  float* out = (float*)d_out;

  char* ws = (char*)d_ws;
  unsigned short* wqkvT  = (unsigned short*)(ws + 0);           //  6 MiB [3072][1024]
  unsigned short* woT    = (unsigned short*)(ws + 6291456);     //  2 MiB [1024][1024]
  unsigned short* w1T    = (unsigned short*)(ws + 8388608);     //  8 MiB [4096][1024]
  unsigned short* w2T    = (unsigned short*)(ws + 16777216);    //  8 MiB [1024][4096]
  unsigned short* attno  = (unsigned short*)(ws + 25165824);    //  8 MiB [4096][1024]
  float*          x2     = (float*)         (ws + 33554432);    // 16 MiB [4096][1024]
  unsigned short* hbuf   = (unsigned short*)(ws + 50331648);    //  8 MiB h1 then h2
  unsigned short* qkvb   = (unsigned short*)(ws + 58720256);    // 24 MiB [4096][3072]
  unsigned short* vtb    = (unsigned short*)(ws + 83886080);    //  8 MiB [32][64][2048]
  unsigned short* gbuf   = (unsigned short*)(ws + 58720256);    // 32 MiB, reuses qkv+vt

  ln_kernel<<<ROWS/4, 256, 0, stream>>>(x, ln1w, ln1b, hbuf);
  wtrans_kernel<<<dim3(32, 32),  256, 0, stream>>>(wq,  wqkvT,                 1024, 1024);
  wtrans_kernel<<<dim3(32, 32),  256, 0, stream>>>(wk,  wqkvT + 1024*1024,     1024, 1024);
  wtrans_kernel<<<dim3(32, 32),  256, 0, stream>>>(wvp, wqkvT + 2*1024*1024,   1024, 1024);
  wtrans_kernel<<<dim3(32, 32),  256, 0, stream>>>(wo,  woT,                   1024, 1024);
  wtrans_kernel<<<dim3(128, 32), 256, 0, stream>>>(w1,  w1T,                   1024, 4096);
  wtrans_kernel<<<dim3(32, 128), 256, 0, stream>>>(w2,  w2T,                   4096, 1024);
  gemm_bt<0><<<dim3(3072/128, 4096/128), 256, 0, stream>>>(hbuf, wqkvT, qkvb, nullptr, ROWS, 3072, 1024);
  vt_kernel<<<dim3(SEQ/64, BATCH*NHEAD), 256, 0, stream>>>(qkvb, vtb);
  attn_kernel<<<dim3(SEQ/64, BATCH*NHEAD), 256, 0, stream>>>(qkvb, vtb, mask, attno);
  gemm_bt<2><<<dim3(1024/128, 4096/128), 256, 0, stream>>>(attno, woT, x2, x, ROWS, 1024, 1024);
  ln_kernel<<<ROWS/4, 256, 0, stream>>>(x2, ln2w, ln2b, hbuf);
  gemm_bt<1><<<dim3(4096/128, 4096/128), 256, 0, stream>>>(hbuf, w1T, gbuf, nullptr, ROWS, FFNSZ, 1024);
  gemm_bt<2><<<dim3(1024/128, 4096/128), 256, 0, stream>>>(gbuf, w2T, out, x2, ROWS, 1024, 4096);

  (void)in_sizes; (void)n_in; (void)out_size; (void)ws_size;
}

// Round 3
// 475.802 us; speedup vs baseline: 1.4002x; 1.0329x over previous
//
#include <hip/hip_runtime.h>
#include <math.h>

// ---------------------------------------------------------------------------
// TransformerBlock: B=2 S=2048 DIM=1024 H=16 hd=64 FFN=4096, fp32 in/out.
// bf16 MFMA everywhere. R2: attention softmax de-VALU'd — fixed-base exp2
// (no online max; exact by shift-invariance, safe at these score magnitudes),
// P packed to bf16 via v_perm truncation (1 instr / 2 vals), mask loaded
// straight to registers (Ms LDS tile deleted; 43K -> 25.6K LDS/block).
// ---------------------------------------------------------------------------

#define DIMSZ 1024
#define SEQ   2048
#define BATCH 2
#define NHEAD 16
#define HD    64
#define FFNSZ 4096
#define ROWS  (BATCH*SEQ)   // 4096

typedef __attribute__((ext_vector_type(8))) short bf8_t;   // 8 x bf16 (4 VGPR)
typedef __attribute__((ext_vector_type(4))) float f4_t;    // 4 x f32

// round-to-nearest-even float -> bf16 (bit pattern)
__device__ __forceinline__ unsigned short f2bf(float f) {
  union { float f; unsigned u; } c; c.f = f;
  unsigned u = c.u;
  return (unsigned short)((u + 0x7fffu + ((u >> 16) & 1u)) >> 16);
}

__device__ __forceinline__ float fast_exp2(float x) {
#if __has_builtin(__builtin_amdgcn_exp2f)
  return __builtin_amdgcn_exp2f(x);   // v_exp_f32 is natively 2^x
#else
  return exp2f(x);
#endif
}

// pack hi16(a),hi16(b) -> (bf16(b)<<16)|bf16(a)  [truncating cvt, 1 instr]
__device__ __forceinline__ unsigned int pk_trunc_bf16(float a, float b) {
#if __has_builtin(__builtin_amdgcn_perm)
  return __builtin_amdgcn_perm(__float_as_uint(b), __float_as_uint(a), 0x07060302u);
#else
  return (__float_as_uint(b) & 0xffff0000u) | (__float_as_uint(a) >> 16);
#endif
}

__device__ __forceinline__ void async16(const void* g, void* l) {
  __builtin_amdgcn_global_load_lds((const __attribute__((address_space(1))) void*)g,
                                   (__attribute__((address_space(3))) void*)l,
                                   16, 0, 0);
}

__device__ __forceinline__ f4_t mfma_bf16(bf8_t a, bf8_t b, f4_t c) {
  return __builtin_amdgcn_mfma_f32_16x16x32_bf16(a, b, c, 0, 0, 0);
}

// ---------------------------------------------------------------------------
// LayerNorm: one wave per row of 1024 fp32 -> bf16 out.
// ---------------------------------------------------------------------------
__global__ __launch_bounds__(256) void ln_kernel(const float* __restrict__ x,
                                                 const float* __restrict__ w,
                                                 const float* __restrict__ b,
                                                 unsigned short* __restrict__ out) {
  int row  = blockIdx.x * 4 + (threadIdx.x >> 6);
  int lane = threadIdx.x & 63;
  const float4* xr = (const float4*)(x + (size_t)row * DIMSZ);
  float4 v[4];
  float s = 0.f, s2 = 0.f;
#pragma unroll
  for (int i = 0; i < 4; ++i) {
    v[i] = xr[lane + 64*i];
    s  += (v[i].x + v[i].y) + (v[i].z + v[i].w);
    s2 += (v[i].x*v[i].x + v[i].y*v[i].y) + (v[i].z*v[i].z + v[i].w*v[i].w);
  }
#pragma unroll
  for (int off = 32; off; off >>= 1) {
    s  += __shfl_xor(s,  off);
    s2 += __shfl_xor(s2, off);
  }
  float mean = s * (1.f/DIMSZ);
  float var  = s2 * (1.f/DIMSZ) - mean*mean;
  float rstd = rsqrtf(var + 1e-12f);
  const float4* wr = (const float4*)w;
  const float4* br = (const float4*)b;
#pragma unroll
  for (int i = 0; i < 4; ++i) {
    float4 wv = wr[lane + 64*i];
    float4 bv = br[lane + 64*i];
    ushort4 o;
    o.x = f2bf((v[i].x - mean) * rstd * wv.x + bv.x);
    o.y = f2bf((v[i].y - mean) * rstd * wv.y + bv.y);
    o.z = f2bf((v[i].z - mean) * rstd * wv.z + bv.z);
    o.w = f2bf((v[i].w - mean) * rstd * wv.w + bv.w);
    *(ushort4*)(out + (size_t)row * DIMSZ + (size_t)(lane + 64*i) * 4) = o;
  }
}

// ---------------------------------------------------------------------------
// Weight cast+transpose: w[K][N] fp32 -> wT[N][K] bf16. 32x32 tiles.
// ---------------------------------------------------------------------------
__global__ __launch_bounds__(256) void wtrans_kernel(const float* __restrict__ w,
                                                     unsigned short* __restrict__ wT,
                                                     int K, int N) {
  __shared__ float t[32][33];
  int tx = threadIdx.x & 31, ty = threadIdx.x >> 5;
  int n0 = blockIdx.x * 32, k0 = blockIdx.y * 32;
#pragma unroll
  for (int i = 0; i < 4; ++i)
    t[ty + 8*i][tx] = w[(size_t)(k0 + ty + 8*i) * N + n0 + tx];
  __syncthreads();
#pragma unroll
  for (int i = 0; i < 4; ++i)
    wT[(size_t)(n0 + ty + 8*i) * K + k0 + tx] = f2bf(t[tx][ty + 8*i]);
}

// ---------------------------------------------------------------------------
// V transpose: qkv[(b*S+s)*3072 + 2048 + h*64 + d] -> vt[(bh*64+d)*S + s]
// ---------------------------------------------------------------------------
__global__ __launch_bounds__(256) void vt_kernel(const unsigned short* __restrict__ qkv,
                                                 unsigned short* __restrict__ vt) {
  __shared__ unsigned short tile[64][65];
  int bh = blockIdx.y, b = bh >> 4, h = bh & 15;
  int s0 = blockIdx.x * 64;
  int tx = threadIdx.x & 63, ty = threadIdx.x >> 6;
#pragma unroll
  for (int i = 0; i < 16; ++i) {
    int s = ty + i*4;
    tile[s][tx] = qkv[((size_t)(b*SEQ) + s0 + s) * 3072 + 2048 + h*HD + tx];
  }
  __syncthreads();
#pragma unroll
  for (int i = 0; i < 16; ++i) {
    int d = ty + i*4;
    vt[((size_t)bh * HD + d) * SEQ + s0 + tx] = tile[tx][d];
  }
}

// ---------------------------------------------------------------------------
// GEMM: C[M,N] = epi( A[M,K] @ Bt[N,K]^T )   (m97 structure, unchanged)
// ---------------------------------------------------------------------------
template<int EPI>
__global__ __launch_bounds__(256) void gemm_bt(const unsigned short* __restrict__ A,
                                               const unsigned short* __restrict__ Bt,
                                               void* __restrict__ Cv,
                                               const float* __restrict__ res,
                                               int M, int N, int K) {
  __shared__ unsigned short As[128*32];
  __shared__ unsigned short Bs[128*32];
  int tid  = threadIdx.x;
  int wv   = tid >> 6, lane = tid & 63, quad = lane >> 4, ml = lane & 15;
  int wrow = (wv >> 1) * 64, wcol = (wv & 1) * 64;
  const unsigned short* Ab = A  + (size_t)blockIdx.y * 128 * K;
  const unsigned short* Bb = Bt + (size_t)blockIdx.x * 128 * K;

  f4_t acc[4][4];
#pragma unroll
  for (int i = 0; i < 4; ++i)
#pragma unroll
    for (int j = 0; j < 4; ++j) acc[i][j] = (f4_t){0.f, 0.f, 0.f, 0.f};

  int r0 = tid >> 2, c0 = (tid & 3) * 8;

  for (int k0 = 0; k0 < K; k0 += 32) {
    async16(Ab + (size_t)r0 * K + k0 + c0,        &As[(size_t)tid * 8]);
    async16(Ab + (size_t)(r0+64) * K + k0 + c0,   &As[((size_t)tid + 256) * 8]);
    async16(Bb + (size_t)r0 * K + k0 + c0,        &Bs[(size_t)tid * 8]);
    async16(Bb + (size_t)(r0+64) * K + k0 + c0,   &Bs[((size_t)tid + 256) * 8]);
    __syncthreads();

    bf8_t af[4], bfr[4];
#pragma unroll
    for (int i = 0; i < 4; ++i)
      af[i] = *(const bf8_t*)(&As[(wrow + i*16 + ml) * 32 + quad * 8]);
#pragma unroll
    for (int j = 0; j < 4; ++j)
      bfr[j] = *(const bf8_t*)(&Bs[(wcol + j*16 + ml) * 32 + quad * 8]);
#pragma unroll
    for (int i = 0; i < 4; ++i)
#pragma unroll
      for (int j = 0; j < 4; ++j)
        acc[i][j] = mfma_bf16(af[i], bfr[j], acc[i][j]);
    __syncthreads();
  }

#pragma unroll
  for (int i = 0; i < 4; ++i) {
    int grow = blockIdx.y * 128 + wrow + i*16 + quad*4;
#pragma unroll
    for (int j = 0; j < 4; ++j) {
      int gcol = blockIdx.x * 128 + wcol + j*16 + ml;
#pragma unroll
      for (int r = 0; r < 4; ++r) {
        size_t off = (size_t)(grow + r) * N + gcol;
        float v = acc[i][j][r];
        if constexpr (EPI == 2) {
          ((float*)Cv)[off] = res[off] + v;
        } else {
          if constexpr (EPI == 1)
            v = 0.5f * v * (1.f + erff(v * 0.70710678118654752f));
          ((unsigned short*)Cv)[off] = f2bf(v);
        }
      }
    }
  }
}

// ---------------------------------------------------------------------------
// Flash attention, R2. grid = (S/64, B*H), block 256 (4 waves x 16 q-rows).
// 64-key chunks, K/V via global_load_lds. Fixed-base exp2 softmax (no online
// max — softmax is shift-invariant; |scores| ~ O(3) here so fp32 exp2 is
// safe, and -inf masks still map to 0). l reduced across quads ONCE at end.
// Mask goes straight to registers (issued before barriers: latency hidden).
// S^T = K·Q^T (A=K m=key, B=Q n=q); O^T = V^T·P^T. P wave-private in LDS.
// ---------------------------------------------------------------------------
__global__ __launch_bounds__(256) void attn_kernel(const unsigned short* __restrict__ qkv,
                                                   const unsigned short* __restrict__ vt,
                                                   const float* __restrict__ mask,
                                                   unsigned short* __restrict__ attnout) {
  __shared__ unsigned short Ks[2][64][32];   // [d-half][key][d32]   8 KB
  __shared__ unsigned short Vs[2][64][32];   // [key-half][d][k32]   8 KB
  __shared__ unsigned short Ps[4][16][72];   // per-wave P^T, padded 9 KB

  int bh = blockIdx.y, b = bh >> 4, h = bh & 15;
  int tid = threadIdx.x;
  int wv = tid >> 6, lane = tid & 63;
  int quad = lane >> 4, ml = lane & 15;
  int q0 = blockIdx.x * 64;
  int q  = q0 + wv * 16 + ml;               // this lane's q row (seq pos)

  // Q fragment, B-operand layout: n=q (lane&15), k=d (quad*8+j)
  const unsigned short* qrow = qkv + ((size_t)(b*SEQ) + q) * 3072 + h*HD;
  bf8_t qf0 = *(const bf8_t*)(qrow + quad*8);
  bf8_t qf1 = *(const bf8_t*)(qrow + 32 + quad*8);

  const unsigned short* kbase = qkv + (size_t)(b*SEQ) * 3072 + DIMSZ + h*HD;
  const unsigned short* vbase = vt + (size_t)bh * HD * SEQ;
  const float* mrow = mask + (size_t)q * SEQ;

  int srow = tid >> 2;            // 0..63
  int scol = (tid & 3) * 8;       // 0,8,16,24 (ushorts)

  f4_t O[4];
#pragma unroll
  for (int dt = 0; dt < 4; ++dt) O[dt] = (f4_t){0.f, 0.f, 0.f, 0.f};
  float lR = 0.f;                 // quad-partial sum of exp

  const float C1 = 0.18033688011112042f;   // 0.125 * log2(e)
  const float C2 = 1.4426950408889634f;    // log2(e)

  for (int t0 = 0; t0 < SEQ; t0 += 64) {
    // mask tile for this lane's q, 4x float4 (VMEM; hidden under barriers)
    float4 mv[4];
#pragma unroll
    for (int mt = 0; mt < 4; ++mt)
      mv[mt] = *(const float4*)(mrow + t0 + mt*16 + quad*4);

    __syncthreads();   // previous chunk's K/V reads done before overwrite
#pragma unroll
    for (int dh = 0; dh < 2; ++dh)
      async16(kbase + (size_t)(t0 + srow) * 3072 + dh*32 + scol,
              &Ks[dh][0][0] + (size_t)tid * 8);
#pragma unroll
    for (int kc = 0; kc < 2; ++kc)
      async16(vbase + (size_t)srow * SEQ + t0 + kc*32 + scol,
              &Vs[kc][0][0] + (size_t)tid * 8);
    __syncthreads();   // staging visible

    // --- S^T = K·Q^T over 64 keys; p = exp2(s*C1 + mask*C2) ---
#pragma unroll
    for (int mt = 0; mt < 4; ++mt) {
      bf8_t kf0 = *(const bf8_t*)(&Ks[0][mt*16 + ml][quad*8]);
      bf8_t kf1 = *(const bf8_t*)(&Ks[1][mt*16 + ml][quad*8]);
      f4_t s = (f4_t){0.f, 0.f, 0.f, 0.f};
      s = mfma_bf16(kf0, qf0, s);
      s = mfma_bf16(kf1, qf1, s);
      float p0 = fast_exp2(fmaf(s[0], C1, mv[mt].x * C2));
      float p1 = fast_exp2(fmaf(s[1], C1, mv[mt].y * C2));
      float p2 = fast_exp2(fmaf(s[2], C1, mv[mt].z * C2));
      float p3 = fast_exp2(fmaf(s[3], C1, mv[mt].w * C2));
      lR += (p0 + p1) + (p2 + p3);
      unsigned int u01 = pk_trunc_bf16(p0, p1);
      unsigned int u23 = pk_trunc_bf16(p2, p3);
      uint2 pk; pk.x = u01; pk.y = u23;
      *(uint2*)(&Ps[wv][ml][mt*16 + quad*4]) = pk;   // P^T[q][4 keys]
    }

    // --- O^T += V^T·P^T (P wave-private: lgkmcnt orders write->read) ---
#pragma unroll
    for (int kc = 0; kc < 2; ++kc) {
      bf8_t pf = *(const bf8_t*)(&Ps[wv][ml][kc*32 + quad*8]);
#pragma unroll
      for (int dt = 0; dt < 4; ++dt) {
        bf8_t vf = *(const bf8_t*)(&Vs[kc][dt*16 + ml][quad*8]);
        O[dt] = mfma_bf16(vf, pf, O[dt]);
      }
    }
  }

  // l: reduce quad partials (lanes sharing ml) once
  lR += __shfl_xor(lR, 16);
  lR += __shfl_xor(lR, 32);
  float linv = 1.f / lR;
#pragma unroll
  for (int dt = 0; dt < 4; ++dt) {
    ushort4 o;
    o.x = f2bf(O[dt][0] * linv);
    o.y = f2bf(O[dt][1] * linv);
    o.z = f2bf(O[dt][2] * linv);
    o.w = f2bf(O[dt][3] * linv);
    *(ushort4*)(attnout + ((size_t)(b*SEQ) + q) * DIMSZ + h*HD + dt*16 + quad*4) = o;
  }
}

// ---------------------------------------------------------------------------
extern "C" void kernel_launch(void* const* d_in, const int* in_sizes, int n_in,
                              void* d_out, int out_size, void* d_ws, size_t ws_size,
                              hipStream_t stream) {
  const float* x    = (const float*)d_in[0];
  const float* mask = (const float*)d_in[1];
  const float* wq   = (const float*)d_in[2];
  const float* wk   = (const float*)d_in[3];
  const float* wvp  = (const float*)d_in[4];
  const float* wo   = (const float*)d_in[5];
  const float* w1   = (const float*)d_in[6];
  const float* w2   = (const float*)d_in[7];
  const float* ln1w = (const float*)d_in[8];
  const float* ln1b = (const float*)d_in[9];
  const float* ln2w = (const float*)d_in[10];
  const float* ln2b = (const float*)d_in[11];
  float* out = (float*)d_out;

  char* ws = (char*)d_ws;
  unsigned short* wqkvT  = (unsigned short*)(ws + 0);           //  6 MiB [3072][1024]
  unsigned short* woT    = (unsigned short*)(ws + 6291456);     //  2 MiB [1024][1024]
  unsigned short* w1T    = (unsigned short*)(ws + 8388608);     //  8 MiB [4096][1024]
  unsigned short* w2T    = (unsigned short*)(ws + 16777216);    //  8 MiB [1024][4096]
  unsigned short* attno  = (unsigned short*)(ws + 25165824);    //  8 MiB [4096][1024]
  float*          x2     = (float*)         (ws + 33554432);    // 16 MiB [4096][1024]
  unsigned short* hbuf   = (unsigned short*)(ws + 50331648);    //  8 MiB h1 then h2
  unsigned short* qkvb   = (unsigned short*)(ws + 58720256);    // 24 MiB [4096][3072]
  unsigned short* vtb    = (unsigned short*)(ws + 83886080);    //  8 MiB [32][64][2048]
  unsigned short* gbuf   = (unsigned short*)(ws + 58720256);    // 32 MiB, reuses qkv+vt

  ln_kernel<<<ROWS/4, 256, 0, stream>>>(x, ln1w, ln1b, hbuf);
  wtrans_kernel<<<dim3(32, 32),  256, 0, stream>>>(wq,  wqkvT,                 1024, 1024);
  wtrans_kernel<<<dim3(32, 32),  256, 0, stream>>>(wk,  wqkvT + 1024*1024,     1024, 1024);
  wtrans_kernel<<<dim3(32, 32),  256, 0, stream>>>(wvp, wqkvT + 2*1024*1024,   1024, 1024);
  wtrans_kernel<<<dim3(32, 32),  256, 0, stream>>>(wo,  woT,                   1024, 1024);
  wtrans_kernel<<<dim3(128, 32), 256, 0, stream>>>(w1,  w1T,                   1024, 4096);
  wtrans_kernel<<<dim3(32, 128), 256, 0, stream>>>(w2,  w2T,                   4096, 1024);
  gemm_bt<0><<<dim3(3072/128, 4096/128), 256, 0, stream>>>(hbuf, wqkvT, qkvb, nullptr, ROWS, 3072, 1024);
  vt_kernel<<<dim3(SEQ/64, BATCH*NHEAD), 256, 0, stream>>>(qkvb, vtb);
  attn_kernel<<<dim3(SEQ/64, BATCH*NHEAD), 256, 0, stream>>>(qkvb, vtb, mask, attno);
  gemm_bt<2><<<dim3(1024/128, 4096/128), 256, 0, stream>>>(attno, woT, x2, x, ROWS, 1024, 1024);
  ln_kernel<<<ROWS/4, 256, 0, stream>>>(x2, ln2w, ln2b, hbuf);
  gemm_bt<1><<<dim3(4096/128, 4096/128), 256, 0, stream>>>(hbuf, w1T, gbuf, nullptr, ROWS, FFNSZ, 1024);
  gemm_bt<2><<<dim3(1024/128, 4096/128), 256, 0, stream>>>(gbuf, w2T, out, x2, ROWS, 1024, 4096);

  (void)in_sizes; (void)n_in; (void)out_size; (void)ws_size;
}